// Round 5
// baseline (18.926 us; speedup 1.0000x reference)
//
#include <hip/hip_runtime.h>

// q[n] = v^T M v, v = deg-2 Veronese (28) of xh=[1,x]. MFMA path:
//   W = M~ * V~  (32x32 padded M, bf16-split, mfma_f32_32x32x16_bf16, 2 K-steps)
//   q[n] = sum_j v[j][n] * W[j][n]   (f32 VALU, lane-local)
// Split: f = hi + lo, hi = bf16-trunc(f), lo = bf16-trunc(f - hi).
// Products kept: Mhi*vhi + Mhi*vlo + Mlo*vhi (drop lo*lo, ~2^-16 rel).
// Layouts (32x32x16): A row = lane&31, B col = lane&31,
//   k(elem e) = 16*s + (e<4 ? e : e+4) + 4*(lane>>5)   [two 4-elem K-slabs]
// C/D: col = lane&31, row = (reg&3) + 8*(reg>>2) + 4*(lane>>5)  [verified m74/m101]
// Every lane only handles point n = tile*32 + (lane&31): fully lane-local.

typedef float f32x16 __attribute__((ext_vector_type(16)));
typedef short bf16x8 __attribute__((ext_vector_type(8)));
typedef unsigned int u32;
typedef u32 u32x4 __attribute__((ext_vector_type(4)));

__device__ __forceinline__ u32   f2u(float f){ return __builtin_bit_cast(u32, f); }
__device__ __forceinline__ float u2f(u32 u)  { return __builtin_bit_cast(float, u); }

// one u32 = (bf16_trunc(b) << 16) | bf16_trunc(a)  -- single v_perm_b32
__device__ __forceinline__ u32 pack2(float a, float b){
    return __builtin_amdgcn_perm(f2u(b), f2u(a), 0x07060302u);
}

// 8 f32 -> hi/lo bf16x8 fragments (trunc split)
__device__ __forceinline__ void split8(const float (&f)[8], bf16x8& hi, bf16x8& lo){
    float r[8];
    #pragma unroll
    for (int i = 0; i < 8; ++i)
        r[i] = f[i] - u2f(f2u(f[i]) & 0xffff0000u);
    u32x4 h, l;
    #pragma unroll
    for (int i = 0; i < 4; ++i){
        h[i] = pack2(f[2*i], f[2*i+1]);
        l[i] = pack2(r[2*i], r[2*i+1]);
    }
    hi = __builtin_bit_cast(bf16x8, h);
    lo = __builtin_bit_cast(bf16x8, l);
}

__global__ __launch_bounds__(256, 4)
void qmfma_kernel(const float* __restrict__ x, const float* __restrict__ M,
                  float* __restrict__ out, int N, int ntiles)
{
    const int  lane = threadIdx.x & 63;
    const int  col  = lane & 31;
    const bool gu   = (lane & 32) != 0;        // upper 32-lane group
    const int  wave = blockIdx.x * (blockDim.x >> 6) + (threadIdx.x >> 6);
    const int  nwaves = gridDim.x * (blockDim.x >> 6);

    // ---- one-time per wave: A fragments of padded M (rows = col index) ----
    bf16x8 Ahi[2], Alo[2];
    #pragma unroll
    for (int s = 0; s < 2; ++s){
        float fa[8];
        #pragma unroll
        for (int e = 0; e < 8; ++e){
            int k = 16*s + (e < 4 ? e : e + 4) + (gu ? 4 : 0);
            bool ok = (col < 28) && (k < 28);
            fa[e] = ok ? M[col * 28 + k] : 0.0f;
        }
        split8(fa, Ahi[s], Alo[s]);
    }

    for (int tile = wave; tile < ntiles; tile += nwaves){
        const int n = tile * 32 + col;

        // ---- Veronese (lane-local, f32) ----
        float v[28];
        v[0] = 1.0f;
        #pragma unroll
        for (int d = 0; d < 6; ++d)
            v[1 + d] = x[d * N + n];
        {
            int vi = 7;
            #pragma unroll
            for (int a = 1; a < 7; ++a)
                #pragma unroll
                for (int b = a; b < 7; ++b)
                    v[vi++] = v[a] * v[b];
        }

        // ---- B fragments (this lane's point, split) ----
        bf16x8 Bhi[2], Blo[2];
        #pragma unroll
        for (int s = 0; s < 2; ++s){
            float fb[8];
            #pragma unroll
            for (int e = 0; e < 8; ++e){
                const int k0 = 16*s + (e < 4 ? e : e + 4); // g=0 slab
                const int k1 = k0 + 4;                     // g=1 slab
                const float v0 = v[k0];
                const float v1 = (k1 < 28) ? v[k1] : 0.0f; // pad k>=28
                fb[e] = gu ? v1 : v0;
            }
            split8(fb, Bhi[s], Blo[s]);
        }

        // ---- W = M~ V~ : 3 split-products x 2 K-steps ----
        f32x16 acc = {};
        acc = __builtin_amdgcn_mfma_f32_32x32x16_bf16(Ahi[0], Bhi[0], acc, 0, 0, 0);
        acc = __builtin_amdgcn_mfma_f32_32x32x16_bf16(Ahi[1], Bhi[1], acc, 0, 0, 0);
        acc = __builtin_amdgcn_mfma_f32_32x32x16_bf16(Ahi[0], Blo[0], acc, 0, 0, 0);
        acc = __builtin_amdgcn_mfma_f32_32x32x16_bf16(Ahi[1], Blo[1], acc, 0, 0, 0);
        acc = __builtin_amdgcn_mfma_f32_32x32x16_bf16(Alo[0], Bhi[0], acc, 0, 0, 0);
        acc = __builtin_amdgcn_mfma_f32_32x32x16_bf16(Alo[1], Bhi[1], acc, 0, 0, 0);

        // ---- q = v . W  (C/D rows this lane holds; rows>=28 are zero) ----
        float partial = 0.0f;
        if (!gu){
            #pragma unroll
            for (int rg = 0; rg < 16; ++rg){
                const int row = (rg & 3) + 8 * (rg >> 2);      // 0..27
                partial = fmaf(v[row], acc[rg], partial);
            }
        } else {
            #pragma unroll
            for (int rg = 0; rg < 12; ++rg){
                const int row = (rg & 3) + 8 * (rg >> 2) + 4;  // 4..23 (skip 28..31)
                partial = fmaf(v[row], acc[rg], partial);
            }
        }
        partial += __shfl_xor(partial, 32);
        if (!gu)
            out[n] = partial;
    }
}

extern "C" void kernel_launch(void* const* d_in, const int* in_sizes, int n_in,
                              void* d_out, int out_size, void* d_ws, size_t ws_size,
                              hipStream_t stream)
{
    const float* x   = (const float*)d_in[0];   // 6*N floats (flat-reshaped)
    const float* M   = (const float*)d_in[1];   // 28*28 floats
    float* out       = (float*)d_out;           // N floats
    const int N      = out_size;                // 1,000,000
    const int ntiles = N / 32;                  // 31250 (exact)

    const int block = 256;                      // 4 waves
    const int grid  = 1954;                     // ~4 tiles per wave
    qmfma_kernel<<<grid, block, 0, stream>>>(x, M, out, N, ntiles);
}

// Round 6
// 17.318 us; speedup vs baseline: 1.0928x; 1.0928x over previous
//
#include <hip/hip_runtime.h>

// q[n] = v^T M v, v = deg-2 Veronese (28) of xh=[1,x]. MFMA path:
//   W = M~ * V~  (32x32 padded M, bf16-split, mfma_f32_32x32x16_bf16, 2 K-steps)
//   q[n] = sum_j v[j][n] * W[j][n]   (f32 VALU, lane-local)
// Split: f = hi + lo (bf16-trunc); keep Mhi*vhi + Mhi*vlo + Mlo*vhi.
// Layouts verified in R5 (absmax 4.0):
//   A row = lane&31, B col = lane&31, k(e) = 16s + (e<4?e:e+4) + 4*(lane>>5)
//   C/D: col = lane&31, row = (rg&3) + 8*(rg>>2) + 4*(lane>>5)
// R6 changes vs R5: register double-buffered x prefetch (next tile's 6 loads
// issued before current tile's MFMA/dot), exact-resident grid (1024 blocks,
// 4/CU, grid-stride ~7.6 tiles/wave).

typedef float f32x16 __attribute__((ext_vector_type(16)));
typedef short bf16x8 __attribute__((ext_vector_type(8)));
typedef unsigned int u32;
typedef u32 u32x4 __attribute__((ext_vector_type(4)));

__device__ __forceinline__ u32   f2u(float f){ return __builtin_bit_cast(u32, f); }
__device__ __forceinline__ float u2f(u32 u)  { return __builtin_bit_cast(float, u); }

// one u32 = (bf16_trunc(b) << 16) | bf16_trunc(a)  -- single v_perm_b32
__device__ __forceinline__ u32 pack2(float a, float b){
    return __builtin_amdgcn_perm(f2u(b), f2u(a), 0x07060302u);
}

// 8 f32 -> hi/lo bf16x8 fragments (trunc split)
__device__ __forceinline__ void split8(const float (&f)[8], bf16x8& hi, bf16x8& lo){
    float r[8];
    #pragma unroll
    for (int i = 0; i < 8; ++i)
        r[i] = f[i] - u2f(f2u(f[i]) & 0xffff0000u);
    u32x4 h, l;
    #pragma unroll
    for (int i = 0; i < 4; ++i){
        h[i] = pack2(f[2*i], f[2*i+1]);
        l[i] = pack2(r[2*i], r[2*i+1]);
    }
    hi = __builtin_bit_cast(bf16x8, h);
    lo = __builtin_bit_cast(bf16x8, l);
}

__global__ __launch_bounds__(256, 4)
void qmfma_kernel(const float* __restrict__ x, const float* __restrict__ M,
                  float* __restrict__ out, int N, int ntiles)
{
    const int  lane = threadIdx.x & 63;
    const int  col  = lane & 31;
    const bool gu   = (lane & 32) != 0;        // upper 32-lane group
    const int  wave = blockIdx.x * (blockDim.x >> 6) + (threadIdx.x >> 6);
    const int  nwaves = gridDim.x * (blockDim.x >> 6);

    // ---- one-time per wave: A fragments of padded M (rows = col index) ----
    bf16x8 Ahi[2], Alo[2];
    #pragma unroll
    for (int s = 0; s < 2; ++s){
        float fa[8];
        #pragma unroll
        for (int e = 0; e < 8; ++e){
            int k = 16*s + (e < 4 ? e : e + 4) + (gu ? 4 : 0);
            bool ok = (col < 28) && (k < 28);
            fa[e] = ok ? M[col * 28 + k] : 0.0f;
        }
        split8(fa, Ahi[s], Alo[s]);
    }

    int tile = wave;
    if (tile >= ntiles) return;

    // prologue: load first tile's x
    float xf[6];
    #pragma unroll
    for (int d = 0; d < 6; ++d)
        xf[d] = x[d * N + tile * 32 + col];

    while (tile < ntiles){
        const int next = tile + nwaves;

        // ---- prefetch next tile's x (hides under MFMA/dot below) ----
        float xf2[6] = {0,0,0,0,0,0};
        if (next < ntiles){
            #pragma unroll
            for (int d = 0; d < 6; ++d)
                xf2[d] = x[d * N + next * 32 + col];
        }

        // ---- Veronese (lane-local, f32) ----
        float v[28];
        v[0] = 1.0f;
        #pragma unroll
        for (int d = 0; d < 6; ++d)
            v[1 + d] = xf[d];
        {
            int vi = 7;
            #pragma unroll
            for (int a = 1; a < 7; ++a)
                #pragma unroll
                for (int b = a; b < 7; ++b)
                    v[vi++] = v[a] * v[b];
        }

        // ---- B fragments (this lane's point, split) ----
        bf16x8 Bhi[2], Blo[2];
        #pragma unroll
        for (int s = 0; s < 2; ++s){
            float fb[8];
            #pragma unroll
            for (int e = 0; e < 8; ++e){
                const int k0 = 16*s + (e < 4 ? e : e + 4); // g=0 slab
                const int k1 = k0 + 4;                     // g=1 slab
                const float v0 = v[k0];
                const float v1 = (k1 < 28) ? v[k1] : 0.0f; // pad k>=28
                fb[e] = gu ? v1 : v0;
            }
            split8(fb, Bhi[s], Blo[s]);
        }

        // ---- W = M~ V~ : 3 split-products x 2 K-steps ----
        f32x16 acc = {};
        acc = __builtin_amdgcn_mfma_f32_32x32x16_bf16(Ahi[0], Bhi[0], acc, 0, 0, 0);
        acc = __builtin_amdgcn_mfma_f32_32x32x16_bf16(Ahi[1], Bhi[1], acc, 0, 0, 0);
        acc = __builtin_amdgcn_mfma_f32_32x32x16_bf16(Ahi[0], Blo[0], acc, 0, 0, 0);
        acc = __builtin_amdgcn_mfma_f32_32x32x16_bf16(Ahi[1], Blo[1], acc, 0, 0, 0);
        acc = __builtin_amdgcn_mfma_f32_32x32x16_bf16(Alo[0], Bhi[0], acc, 0, 0, 0);
        acc = __builtin_amdgcn_mfma_f32_32x32x16_bf16(Alo[1], Bhi[1], acc, 0, 0, 0);

        // ---- q = v . W  (C/D rows this lane holds; rows>=28 are zero) ----
        float partial = 0.0f;
        if (!gu){
            #pragma unroll
            for (int rg = 0; rg < 16; ++rg){
                const int row = (rg & 3) + 8 * (rg >> 2);      // 0..27
                partial = fmaf(v[row], acc[rg], partial);
            }
        } else {
            #pragma unroll
            for (int rg = 0; rg < 12; ++rg){
                const int row = (rg & 3) + 8 * (rg >> 2) + 4;  // 4..23 (skip 28..31)
                partial = fmaf(v[row], acc[rg], partial);
            }
        }
        partial += __shfl_xor(partial, 32);
        if (!gu)
            out[tile * 32 + col] = partial;

        // rotate prefetch buffer
        #pragma unroll
        for (int d = 0; d < 6; ++d)
            xf[d] = xf2[d];
        tile = next;
    }
}

extern "C" void kernel_launch(void* const* d_in, const int* in_sizes, int n_in,
                              void* d_out, int out_size, void* d_ws, size_t ws_size,
                              hipStream_t stream)
{
    const float* x   = (const float*)d_in[0];   // 6*N floats (flat-reshaped)
    const float* M   = (const float*)d_in[1];   // 28*28 floats
    float* out       = (float*)d_out;           // N floats
    const int N      = out_size;                // 1,000,000
    const int ntiles = N / 32;                  // 31250 (exact)

    const int block = 256;                      // 4 waves
    const int grid  = 1024;                     // exactly 4 blocks/CU resident
    qmfma_kernel<<<grid, block, 0, stream>>>(x, M, out, N, ntiles);
}

// Round 7
// 14.967 us; speedup vs baseline: 1.2645x; 1.1571x over previous
//
#include <hip/hip_runtime.h>

// q[n] = v^T M v, v = deg-2 Veronese (28) of xh=[1,x]. MFMA path:
//   W = (Mhi+Mlo) * Vhi   (32x32 padded M, mfma_f32_32x32x16_bf16, 4 MFMAs)
//   q[n] = sum_rg w[rg] * acc[rg]  (f32 VALU, branch-free)
// Layouts verified in R5/R6 (absmax 4.0):
//   A row = lane&31, B col = lane&31, k(e) = 16s + (e<4?e:e+4) + 4*(lane>>5)
//   C/D:  col = lane&31, row = (rg&3) + 8*(rg>>2) + 4*(lane>>5)
// R7 key trick: base[rg] = (rg&3)+8*(rg>>2) gives the SAME 16 base indices
// for B-frag k-slabs (Bfrag[s][e] = w[8s+e]) and C/D dot rows, shifted +4 for
// the upper half-wave. One 16-wide cndmask select w[] feeds both: packs need
// no further selection, dot is branch-free. B carries only the bf16-hi part
// (error ~q*2^-8, well under threshold); M keeps the hi+lo split.

typedef float f32x16 __attribute__((ext_vector_type(16)));
typedef short bf16x8 __attribute__((ext_vector_type(8)));
typedef unsigned int u32;
typedef u32 u32x4 __attribute__((ext_vector_type(4)));

__device__ __forceinline__ u32   f2u(float f){ return __builtin_bit_cast(u32, f); }
__device__ __forceinline__ float u2f(u32 u)  { return __builtin_bit_cast(float, u); }

// one u32 = (bf16_trunc(b) << 16) | bf16_trunc(a)  -- single v_perm_b32
__device__ __forceinline__ u32 pack2(float a, float b){
    return __builtin_amdgcn_perm(f2u(b), f2u(a), 0x07060302u);
}

// 8 f32 -> hi/lo bf16x8 fragments (trunc split) -- A-side one-time only
__device__ __forceinline__ void split8(const float (&f)[8], bf16x8& hi, bf16x8& lo){
    float r[8];
    #pragma unroll
    for (int i = 0; i < 8; ++i)
        r[i] = f[i] - u2f(f2u(f[i]) & 0xffff0000u);
    u32x4 h, l;
    #pragma unroll
    for (int i = 0; i < 4; ++i){
        h[i] = pack2(f[2*i], f[2*i+1]);
        l[i] = pack2(r[2*i], r[2*i+1]);
    }
    hi = __builtin_bit_cast(bf16x8, h);
    lo = __builtin_bit_cast(bf16x8, l);
}

__global__ __launch_bounds__(256, 4)
void qmfma_kernel(const float* __restrict__ x, const float* __restrict__ M,
                  float* __restrict__ out, int N, int ntiles)
{
    const int  lane = threadIdx.x & 63;
    const int  col  = lane & 31;
    const bool gu   = (lane & 32) != 0;        // upper 32-lane group
    const int  wave = blockIdx.x * (blockDim.x >> 6) + (threadIdx.x >> 6);
    const int  nwaves = gridDim.x * (blockDim.x >> 6);

    // ---- one-time per wave: A fragments of padded M (row = col index) ----
    bf16x8 Ahi[2], Alo[2];
    #pragma unroll
    for (int s = 0; s < 2; ++s){
        float fa[8];
        #pragma unroll
        for (int e = 0; e < 8; ++e){
            int k = 16*s + (e < 4 ? e : e + 4) + (gu ? 4 : 0);
            bool ok = (col < 28) && (k < 28);
            fa[e] = ok ? M[col * 28 + k] : 0.0f;
        }
        split8(fa, Ahi[s], Alo[s]);
    }

    int tile = wave;
    if (tile >= ntiles) return;

    float xf[6];
    #pragma unroll
    for (int d = 0; d < 6; ++d)
        xf[d] = x[d * N + tile * 32 + col];

    while (tile < ntiles){
        const int next = tile + nwaves;

        // ---- prefetch next tile's x (hides under MFMA/dot below) ----
        float xf2[6] = {0,0,0,0,0,0};
        if (next < ntiles){
            #pragma unroll
            for (int d = 0; d < 6; ++d)
                xf2[d] = x[d * N + next * 32 + col];
        }

        // ---- Veronese (lane-local, f32) ----
        float v[28];
        v[0] = 1.0f;
        #pragma unroll
        for (int d = 0; d < 6; ++d)
            v[1 + d] = xf[d];
        {
            int vi = 7;
            #pragma unroll
            for (int a = 1; a < 7; ++a)
                #pragma unroll
                for (int b = a; b < 7; ++b)
                    v[vi++] = v[a] * v[b];
        }

        // ---- single 16-wide select feeds both B-frags and the dot ----
        // w[rg] = v[base[rg] + 4*gu], base[rg] = (rg&3) + 8*(rg>>2)
        float w[16];
        #pragma unroll
        for (int rg = 0; rg < 16; ++rg){
            const int base = (rg & 3) + 8 * (rg >> 2);
            const float hi_v = (base + 4 < 28) ? v[base + 4] : 0.0f;
            w[rg] = gu ? hi_v : v[base];
        }

        // ---- B fragments: Bfrag[s][e] = bf16(w[8s+e]), straight pack ----
        bf16x8 Bhi[2];
        #pragma unroll
        for (int s = 0; s < 2; ++s){
            u32x4 h;
            #pragma unroll
            for (int i = 0; i < 4; ++i)
                h[i] = pack2(w[8*s + 2*i], w[8*s + 2*i + 1]);
            Bhi[s] = __builtin_bit_cast(bf16x8, h);
        }

        // ---- W = M~ Vhi : (hi + lo) x 2 K-steps = 4 MFMAs ----
        f32x16 acc = {};
        acc = __builtin_amdgcn_mfma_f32_32x32x16_bf16(Ahi[0], Bhi[0], acc, 0, 0, 0);
        acc = __builtin_amdgcn_mfma_f32_32x32x16_bf16(Ahi[1], Bhi[1], acc, 0, 0, 0);
        acc = __builtin_amdgcn_mfma_f32_32x32x16_bf16(Alo[0], Bhi[0], acc, 0, 0, 0);
        acc = __builtin_amdgcn_mfma_f32_32x32x16_bf16(Alo[1], Bhi[1], acc, 0, 0, 0);

        // ---- q = w . acc (branch-free; rows 28..31 are zero both sides) ----
        float partial = 0.0f;
        #pragma unroll
        for (int rg = 0; rg < 16; ++rg)
            partial = fmaf(w[rg], acc[rg], partial);
        partial += __shfl_xor(partial, 32);
        if (!gu)
            out[tile * 32 + col] = partial;

        #pragma unroll
        for (int d = 0; d < 6; ++d)
            xf[d] = xf2[d];
        tile = next;
    }
}

extern "C" void kernel_launch(void* const* d_in, const int* in_sizes, int n_in,
                              void* d_out, int out_size, void* d_ws, size_t ws_size,
                              hipStream_t stream)
{
    const float* x   = (const float*)d_in[0];   // 6*N floats (flat-reshaped)
    const float* M   = (const float*)d_in[1];   // 28*28 floats
    float* out       = (float*)d_out;           // N floats
    const int N      = out_size;                // 1,000,000
    const int ntiles = N / 32;                  // 31250 (exact)

    const int block = 256;                      // 4 waves
    const int grid  = 1024;                     // exactly 4 blocks/CU resident
    qmfma_kernel<<<grid, block, 0, stream>>>(x, M, out, N, ntiles);
}

// Round 8
// 14.537 us; speedup vs baseline: 1.3019x; 1.0296x over previous
//
#include <hip/hip_runtime.h>

// q[n] = v^T M v, v = deg-2 Veronese (28) of xh=[1,x]. MFMA path:
//   W = (Mhi+Mlo) * Vhi   (32x32 padded M, mfma_f32_32x32x16_bf16, 4 MFMAs)
//   q[n] = sum_rg w[rg] * acc[rg]  (f32 VALU, branch-free)
// Layouts verified R5-R7 (absmax 8.0 passes):
//   A row = lane&31, B col = lane&31, k(e) = 16s + (e<4?e:e+4) + 4*(lane>>5)
//   C/D:  col = lane&31, row = (rg&3) + 8*(rg>>2) + 4*(lane>>5)
// w[rg] = v[(rg&3)+8*(rg>>2) + 4*gu] feeds B-frags AND the dot (R7 trick).
// R8 vs R7: persistent ZERO f32x16 as chain-head C operand (no per-tile
// 16-reg re-init), clamped unconditional prefetch (no exec-mask setup),
// hoisted per-row base pointers (1 v_lshl_add + 6 loads per tile).

typedef float f32x16 __attribute__((ext_vector_type(16)));
typedef short bf16x8 __attribute__((ext_vector_type(8)));
typedef unsigned int u32;
typedef u32 u32x4 __attribute__((ext_vector_type(4)));

__device__ __forceinline__ u32   f2u(float f){ return __builtin_bit_cast(u32, f); }
__device__ __forceinline__ float u2f(u32 u)  { return __builtin_bit_cast(float, u); }

// one u32 = (bf16_trunc(b) << 16) | bf16_trunc(a)  -- single v_perm_b32
__device__ __forceinline__ u32 pack2(float a, float b){
    return __builtin_amdgcn_perm(f2u(b), f2u(a), 0x07060302u);
}

// 8 f32 -> hi/lo bf16x8 fragments (trunc split) -- A-side one-time only
__device__ __forceinline__ void split8(const float (&f)[8], bf16x8& hi, bf16x8& lo){
    float r[8];
    #pragma unroll
    for (int i = 0; i < 8; ++i)
        r[i] = f[i] - u2f(f2u(f[i]) & 0xffff0000u);
    u32x4 h, l;
    #pragma unroll
    for (int i = 0; i < 4; ++i){
        h[i] = pack2(f[2*i], f[2*i+1]);
        l[i] = pack2(r[2*i], r[2*i+1]);
    }
    hi = __builtin_bit_cast(bf16x8, h);
    lo = __builtin_bit_cast(bf16x8, l);
}

__global__ __launch_bounds__(256, 4)
void qmfma_kernel(const float* __restrict__ x, const float* __restrict__ M,
                  float* __restrict__ out, int N, int ntiles)
{
    const int  lane = threadIdx.x & 63;
    const int  col  = lane & 31;
    const bool gu   = (lane & 32) != 0;        // upper 32-lane group
    const int  wave = blockIdx.x * (blockDim.x >> 6) + (threadIdx.x >> 6);
    const int  nwaves = gridDim.x * (blockDim.x >> 6);

    // ---- one-time per wave: A fragments of padded M (row = col index) ----
    bf16x8 Ahi[2], Alo[2];
    #pragma unroll
    for (int s = 0; s < 2; ++s){
        float fa[8];
        #pragma unroll
        for (int e = 0; e < 8; ++e){
            int k = 16*s + (e < 4 ? e : e + 4) + (gu ? 4 : 0);
            bool ok = (col < 28) && (k < 28);
            fa[e] = ok ? M[col * 28 + k] : 0.0f;
        }
        split8(fa, Ahi[s], Alo[s]);
    }

    // hoisted per-row bases: per-tile address = base_d + (tile*32 + col)
    const float* xb0 = x;
    const float* xb1 = x + (size_t)N;
    const float* xb2 = x + 2 * (size_t)N;
    const float* xb3 = x + 3 * (size_t)N;
    const float* xb4 = x + 4 * (size_t)N;
    const float* xb5 = x + 5 * (size_t)N;

    int tile = wave;
    if (tile >= ntiles) return;

    // persistent zero C-operand (loop-invariant registers)
    f32x16 ZERO = {};

    float xf[6];
    {
        const int off = tile * 32 + col;
        xf[0] = xb0[off]; xf[1] = xb1[off]; xf[2] = xb2[off];
        xf[3] = xb3[off]; xf[4] = xb4[off]; xf[5] = xb5[off];
    }

    while (tile < ntiles){
        const int next = tile + nwaves;
        // clamped unconditional prefetch (valid address, no exec-mask setup)
        const int pnext = (next < ntiles) ? next : tile;
        float xf2[6];
        {
            const int off = pnext * 32 + col;
            xf2[0] = xb0[off]; xf2[1] = xb1[off]; xf2[2] = xb2[off];
            xf2[3] = xb3[off]; xf2[4] = xb4[off]; xf2[5] = xb5[off];
        }

        // ---- Veronese (lane-local, f32) ----
        float v[28];
        v[0] = 1.0f;
        #pragma unroll
        for (int d = 0; d < 6; ++d)
            v[1 + d] = xf[d];
        {
            int vi = 7;
            #pragma unroll
            for (int a = 1; a < 7; ++a)
                #pragma unroll
                for (int b = a; b < 7; ++b)
                    v[vi++] = v[a] * v[b];
        }

        // ---- single 16-wide select feeds both B-frags and the dot ----
        float w[16];
        #pragma unroll
        for (int rg = 0; rg < 16; ++rg){
            const int base = (rg & 3) + 8 * (rg >> 2);
            const float hi_v = (base + 4 < 28) ? v[base + 4] : 0.0f;
            w[rg] = gu ? hi_v : v[base];
        }

        // ---- B fragments: Bfrag[s][e] = bf16(w[8s+e]), straight pack ----
        bf16x8 Bhi[2];
        #pragma unroll
        for (int s = 0; s < 2; ++s){
            u32x4 h;
            #pragma unroll
            for (int i = 0; i < 4; ++i)
                h[i] = pack2(w[8*s + 2*i], w[8*s + 2*i + 1]);
            Bhi[s] = __builtin_bit_cast(bf16x8, h);
        }

        // ---- W = M~ Vhi : (hi + lo) x 2 K-steps = 4 MFMAs, C = ZERO ----
        f32x16 acc;
        acc = __builtin_amdgcn_mfma_f32_32x32x16_bf16(Ahi[0], Bhi[0], ZERO, 0, 0, 0);
        acc = __builtin_amdgcn_mfma_f32_32x32x16_bf16(Ahi[1], Bhi[1], acc,  0, 0, 0);
        acc = __builtin_amdgcn_mfma_f32_32x32x16_bf16(Alo[0], Bhi[0], acc,  0, 0, 0);
        acc = __builtin_amdgcn_mfma_f32_32x32x16_bf16(Alo[1], Bhi[1], acc,  0, 0, 0);

        // ---- q = w . acc (branch-free; rows 28..31 zero both sides) ----
        float partial = 0.0f;
        #pragma unroll
        for (int rg = 0; rg < 16; ++rg)
            partial = fmaf(w[rg], acc[rg], partial);
        partial += __shfl_xor(partial, 32);
        if (!gu)
            out[tile * 32 + col] = partial;

        #pragma unroll
        for (int d = 0; d < 6; ++d)
            xf[d] = xf2[d];
        tile = next;
    }
}

extern "C" void kernel_launch(void* const* d_in, const int* in_sizes, int n_in,
                              void* d_out, int out_size, void* d_ws, size_t ws_size,
                              hipStream_t stream)
{
    const float* x   = (const float*)d_in[0];   // 6*N floats (flat-reshaped)
    const float* M   = (const float*)d_in[1];   // 28*28 floats
    float* out       = (float*)d_out;           // N floats
    const int N      = out_size;                // 1,000,000
    const int ntiles = N / 32;                  // 31250 (exact)

    const int block = 256;                      // 4 waves
    const int grid  = 1024;                     // 4 blocks/CU resident
    qmfma_kernel<<<grid, block, 0, stream>>>(x, M, out, N, ntiles);
}